// Round 7
// baseline (237.541 us; speedup 1.0000x reference)
//
#include <hip/hip_runtime.h>
#include <math.h>

#define N_NODES 50000
#define N_EDGES 800000
#define IN_DIM 128
#define HID 256
#define NCLASS 40

#define SCAN_NBLK 49   // ceil(50000 / 1024)

// CSR build: 256 privatized histogram blocks, 8-bit packed counters (4 rows/u32)
#define HBLK 256
#define EPB  3125      // edges per hist block: 256 * 3125 = 800000 exactly
#define PK   12500     // packed u32 bins (50000 rows / 4)
#define CS_G 4         // colscan hist groups
#define CS_HPG 64      // hists per group (256/4)

typedef __attribute__((ext_vector_type(8))) short short8;
typedef __attribute__((ext_vector_type(4))) float floatx4;
typedef __attribute__((ext_vector_type(4))) unsigned uintx4;

// ---------- bf16 helpers (RNE pack, cheap unpack) ----------
__device__ inline unsigned bf16pair(float a, float b) {
    unsigned ua = __float_as_uint(a), ub = __float_as_uint(b);
    ua = (ua + 0x7fffu + ((ua >> 16) & 1u)) >> 16;
    ub = (ub + 0x7fffu + ((ub >> 16) & 1u)) >> 16;
    return ua | (ub << 16);
}
__device__ inline unsigned bf16bits(float a) {
    unsigned ua = __float_as_uint(a);
    return (ua + 0x7fffu + ((ua >> 16) & 1u)) >> 16;
}
__device__ inline float bf_lo(unsigned u) { return __uint_as_float(u << 16); }
__device__ inline float bf_hi(unsigned u) { return __uint_as_float(u & 0xffff0000u); }

#define FMA8(A, v, h) do { \
    A[0] += (v) * bf_lo((h).x); A[1] += (v) * bf_hi((h).x); \
    A[2] += (v) * bf_lo((h).y); A[3] += (v) * bf_hi((h).y); \
    A[4] += (v) * bf_lo((h).z); A[5] += (v) * bf_hi((h).z); \
    A[6] += (v) * bf_lo((h).w); A[7] += (v) * bf_hi((h).w); } while (0)

// ---------------- fused prep + hist ----------------
// 256 blocks x 1024: per-block privatized LDS histogram (8-bit packed; degree < 256),
// plus grid-stride feats->bf16 conversion and W1/W2 MFMA fragment packing.
__global__ __launch_bounds__(1024) void prep_hist_kernel(const float4* __restrict__ f4,
                                                         uint2* __restrict__ fb16,
                                                         const float* __restrict__ W1,
                                                         uint4* __restrict__ W1frag,
                                                         const float* __restrict__ W2,
                                                         uint4* __restrict__ W2frag,
                                                         const int* __restrict__ rows,
                                                         unsigned* __restrict__ hist) {
    __shared__ unsigned h[PK];    // 50 KB
    int t = threadIdx.x;
    for (int i = t; i < PK / 4; i += 1024)
        ((uint4*)h)[i] = make_uint4(0u, 0u, 0u, 0u);
    __syncthreads();
    int e0 = blockIdx.x * EPB;
    for (int i = t; i < EPB; i += 1024) {
        int r = rows[e0 + i];
        atomicAdd(&h[r >> 2], 1u << ((r & 3) * 8));   // LDS atomic
    }
    // streaming prep (overlaps atomic settle; no sync needed before it)
    int gid = blockIdx.x * 1024 + t;                  // < 262144
    for (int i = gid; i < N_NODES * IN_DIM / 4; i += HBLK * 1024) {
        float4 v = f4[i];
        fb16[i] = make_uint2(bf16pair(v.x, v.y), bf16pair(v.z, v.w));
    }
    if (gid < 4096) {
        int f = gid;
        int hh = f >> 11, rem = f & 2047;
        int tt = rem >> 8, s = (rem >> 6) & 3, l = rem & 63;
        int q = l >> 4, n16 = l & 15;
        int n = hh * 128 + tt * 16 + n16;
        int kb = s * 32 + q * 8;
        unsigned p[4];
        #pragma unroll
        for (int jj = 0; jj < 4; ++jj) {
            float a = W1[(size_t)(kb + 2 * jj) * HID + n];
            float b = W1[(size_t)(kb + 2 * jj + 1) * HID + n];
            p[jj] = bf16pair(a, b);
        }
        W1frag[f] = make_uint4(p[0], p[1], p[2], p[3]);
    } else if (gid < 4096 + 1536) {
        // W2 B-fragments: [nt(3)][ks(8)][lane(64)], cols padded 40->48 with zeros
        int f2 = gid - 4096;
        int nt = f2 >> 9;
        int rem = f2 & 511;
        int ks = rem >> 6, l = rem & 63;
        int col = nt * 16 + (l & 15);
        int k = ks * 32 + (l >> 4) * 8;
        unsigned p[4];
        #pragma unroll
        for (int jj = 0; jj < 4; ++jj) {
            float a = (col < NCLASS) ? W2[(size_t)(k + 2 * jj) * NCLASS + col] : 0.f;
            float b = (col < NCLASS) ? W2[(size_t)(k + 2 * jj + 1) * NCLASS + col] : 0.f;
            p[jj] = bf16pair(a, b);
        }
        W2frag[f2] = make_uint4(p[0], p[1], p[2], p[3]);
    }
    __syncthreads();
    unsigned* out = hist + (size_t)blockIdx.x * PK;
    for (int i = t; i < PK / 4; i += 1024)
        ((uint4*)out)[i] = ((const uint4*)h)[i];
}

// ---------------- colscan v2: 4-way parallel per-row prefix across 256 block-histograms ----
__global__ __launch_bounds__(1024) void colscan_kernel(const unsigned* __restrict__ hist,
                                                       unsigned* __restrict__ base,
                                                       unsigned* __restrict__ goff,
                                                       int* __restrict__ counts,
                                                       int* __restrict__ blockSums) {
    __shared__ unsigned lsum[CS_G][256];
    int tid = threadIdx.x;          // 1024
    int g = tid >> 8;               // 0..3 hist group
    int c = tid & 255;              // col-quad within block
    int colq = blockIdx.x * 256 + c;
    unsigned run = 0;               // 4 packed 8-bit running sums (degree < 256: no overflow)
    if (colq < PK) {
        #pragma unroll 8
        for (int i = 0; i < CS_HPG; ++i) {
            int b = g * CS_HPG + i;
            unsigned v = hist[(size_t)b * PK + colq];
            base[(size_t)b * PK + colq] = run;
            run += v;
        }
    }
    lsum[g][c] = run;
    __syncthreads();
    unsigned off = 0;
    #pragma unroll
    for (int gg = 0; gg < CS_G; ++gg) {
        unsigned v = lsum[gg][c];
        if (gg < g) off += v;
    }
    unsigned tot = off + run;       // valid for g == CS_G-1: full per-row degrees (packed)
    if (colq < PK) {
        goff[(size_t)g * PK + colq] = off;
        if (g == CS_G - 1)
            *(int4*)(counts + 4 * colq) = make_int4((int)(tot & 0xffu), (int)((tot >> 8) & 0xffu),
                                                    (int)((tot >> 16) & 0xffu), (int)(tot >> 24));
    }
    // per-scanblock edge-count sum (rows [blk*1024, blk*1024+1024))
    int s = 0;
    if (g == CS_G - 1 && colq < PK)
        s = (int)((tot & 0xffu) + ((tot >> 8) & 0xffu) + ((tot >> 16) & 0xffu) + (tot >> 24));
    #pragma unroll
    for (int o = 32; o >= 1; o >>= 1)
        s += __shfl_xor(s, o);
    __shared__ int wsum[16];
    int lane = tid & 63, wid = tid >> 6;
    if (lane == 0) wsum[wid] = s;
    __syncthreads();
    if (tid == 0) {
        int acc = 0;
        #pragma unroll
        for (int i = 0; i < 16; ++i) acc += wsum[i];
        blockSums[blockIdx.x] = acc;
    }
}

// ---------------- local scan (fused block-offset scan) -> row_start ----------------
// NOTE: 256 threads exactly (t*4 covers this block's 1024 rows; wsum sized for 4 waves).
__global__ __launch_bounds__(256) void local_scan_kernel(const int* __restrict__ counts,
                                                         const int* __restrict__ blockSums,
                                                         int* __restrict__ row_start) {
    __shared__ int wsum[4];
    __shared__ int boff;
    int t = threadIdx.x;
    // wave 0: scan the 49 block sums; every block computes its own offset
    if (t < 64) {
        int x = (t < SCAN_NBLK) ? blockSums[t] : 0;
        #pragma unroll
        for (int off = 1; off < 64; off <<= 1) {
            int y = __shfl_up(x, off);
            if (t >= off) x += y;
        }
        int excl = __shfl_up(x, 1);
        if (t == 0) excl = 0;
        if (t == blockIdx.x) boff = excl;
        if (blockIdx.x == SCAN_NBLK - 1 && t == SCAN_NBLK - 1)
            row_start[N_NODES] = x;   // grand total
    }
    int base = blockIdx.x * 1024 + t * 4;
    int4 c = make_int4(0, 0, 0, 0);
    if (base < N_NODES) c = *(const int4*)(counts + base);
    int s0 = c.x, s1 = s0 + c.y, s2 = s1 + c.z, s3 = s2 + c.w;
    int tsum = s3;
    int lane = t & 63, wid = t >> 6;
    int x = tsum;
    #pragma unroll
    for (int off = 1; off < 64; off <<= 1) {
        int y = __shfl_up(x, off);
        if (lane >= off) x += y;
    }
    if (lane == 63) wsum[wid] = x;
    __syncthreads();
    int woff = 0;
    for (int i = 0; i < 4; ++i)
        if (i < wid) woff += wsum[i];
    int excl = x - tsum + woff + boff;
    if (base < N_NODES) {
        int4 rs = make_int4(excl, excl + s0, excl + s1, excl + s2);
        *(int4*)(row_start + base) = rs;
    }
}

// ---------------- scatter2: rank via LDS atomic replay (zero global atomics) ----------------
__global__ __launch_bounds__(1024) void scatter2_kernel(const int* __restrict__ rows,
                                                        const int* __restrict__ cols,
                                                        const float* __restrict__ vals,
                                                        const unsigned* __restrict__ base,
                                                        const unsigned* __restrict__ goff,
                                                        const int* __restrict__ row_start,
                                                        unsigned* __restrict__ csr_cv) {
    __shared__ unsigned cur[PK];  // 50 KB: this block's packed per-row bases
    int t = threadIdx.x;
    const uint4* bb = (const uint4*)(base + (size_t)blockIdx.x * PK);
    const uint4* gg = (const uint4*)(goff + (size_t)(blockIdx.x >> 6) * PK);
    for (int i = t; i < PK / 4; i += 1024) {
        uint4 b = bb[i], o = gg[i];
        // byte-parallel add: per-row sums < 256 so no cross-byte carries
        ((uint4*)cur)[i] = make_uint4(b.x + o.x, b.y + o.y, b.z + o.z, b.w + o.w);
    }
    __syncthreads();
    int e0 = blockIdx.x * EPB;
    for (int i = t; i < EPB; i += 1024) {
        int e = e0 + i;
        int r = rows[e];
        unsigned sh = (unsigned)(r & 3) * 8u;
        unsigned old = atomicAdd(&cur[r >> 2], 1u << sh);   // LDS atomic
        int pos = row_start[r] + (int)((old >> sh) & 0xffu);
        csr_cv[pos] = ((unsigned)cols[e] << 16) | bf16bits(vals[e]);
    }
}

// ---------------- SpMM store helper ----------------
template <int MODE>
__device__ inline void spmm_store(int row, float* acc, int q,
                                  uintx4* __restrict__ Hout4,
                                  const float* __restrict__ feats,
                                  const uintx4* __restrict__ h1b4,
                                  const uintx4* __restrict__ h2b4) {
    size_t o16 = (size_t)row * 16 + q;
    if (MODE == 1) {
        #pragma unroll
        for (int i = 0; i < 8; ++i) acc[i] *= 0.5f;
    } else if (MODE == 2) {
        size_t of = (size_t)row * IN_DIM + q * 8;
        floatx4 f0 = __builtin_nontemporal_load((const floatx4*)(feats + of));
        floatx4 f1 = __builtin_nontemporal_load((const floatx4*)(feats + of + 4));
        uintx4 a = __builtin_nontemporal_load(h1b4 + o16);
        uintx4 b = __builtin_nontemporal_load(h2b4 + o16);
        acc[0] += 0.5f * f0.x + bf_lo(a.x) + bf_lo(b.x);
        acc[1] += 0.5f * f0.y + bf_hi(a.x) + bf_hi(b.x);
        acc[2] += 0.5f * f0.z + bf_lo(a.y) + bf_lo(b.y);
        acc[3] += 0.5f * f0.w + bf_hi(a.y) + bf_hi(b.y);
        acc[4] += 0.5f * f1.x + bf_lo(a.z) + bf_lo(b.z);
        acc[5] += 0.5f * f1.y + bf_hi(a.z) + bf_hi(b.z);
        acc[6] += 0.5f * f1.z + bf_lo(a.w) + bf_lo(b.w);
        acc[7] += 0.5f * f1.w + bf_hi(a.w) + bf_hi(b.w);
    }
    uintx4 rv;
    rv.x = bf16pair(acc[0], acc[1]);
    rv.y = bf16pair(acc[2], acc[3]);
    rv.z = bf16pair(acc[4], acc[5]);
    rv.w = bf16pair(acc[6], acc[7]);
    __builtin_nontemporal_store(rv, Hout4 + o16);
}

// ---------------- SpMM (CSR): TWO rows per wave, dual 4-gather chains ----------------
// Wave handles rows 2w, 2w+1 (CSR-adjacent: one contiguous row_start triple).
// lane = 16p+q. Per 16-edge batch of EACH row: 4 independent dwordx4 gathers ->
// 8 gathers in flight per lane (MLP=8), per-row front overhead halved.
// Zero-padding (u=0 -> col 0, val +0.0) keeps the dual loop exact; pad gathers hit
// the L1-hot row 0.
template <int MODE>
__global__ __launch_bounds__(256) void spmm_csr(const int* __restrict__ row_start,
                                                const unsigned* __restrict__ csr_cv,
                                                const uintx4* __restrict__ Hin4,
                                                uintx4* __restrict__ Hout4,
                                                const float* __restrict__ feats,
                                                const uintx4* __restrict__ h1b4,
                                                const uintx4* __restrict__ h2b4) {
    int wv = (blockIdx.x * blockDim.x + threadIdx.x) >> 6;   // 0..24999
    int lane = threadIdx.x & 63;
    int pr = wv * 2;
    int p = lane >> 4;          // 0..3: which edge of the quad
    int q = lane & 15;          // dim group (8 dims = 16 B)
    int s0 = row_start[pr];
    int e0 = row_start[pr + 1];
    int e1 = row_start[pr + 2];
    float a0[8] = {}, a1[8] = {};
    int b0 = s0, b1 = e0;
    while (b0 < e0 || b1 < e1) {
        unsigned u0 = 0, u1 = 0;
        if (b0 + lane < e0) u0 = __builtin_nontemporal_load(csr_cv + b0 + lane);
        if (b1 + lane < e1) u1 = __builtin_nontemporal_load(csr_cv + b1 + lane);
        int m0 = e0 - b0, m1 = e1 - b1;
        int m = m0 > m1 ? m0 : m1;
        if (m > 64) m = 64;
        for (int j = 0; j < m; j += 16) {
            unsigned x0 = __shfl(u0, j + p);
            unsigned x1 = __shfl(u0, j + 4 + p);
            unsigned x2 = __shfl(u0, j + 8 + p);
            unsigned x3 = __shfl(u0, j + 12 + p);
            unsigned y0 = __shfl(u1, j + p);
            unsigned y1 = __shfl(u1, j + 4 + p);
            unsigned y2 = __shfl(u1, j + 8 + p);
            unsigned y3 = __shfl(u1, j + 12 + p);
            uintx4 hx0 = Hin4[(size_t)(x0 >> 16) * 16 + q];   // 8 gathers in flight
            uintx4 hx1 = Hin4[(size_t)(x1 >> 16) * 16 + q];
            uintx4 hx2 = Hin4[(size_t)(x2 >> 16) * 16 + q];
            uintx4 hx3 = Hin4[(size_t)(x3 >> 16) * 16 + q];
            uintx4 hy0 = Hin4[(size_t)(y0 >> 16) * 16 + q];
            uintx4 hy1 = Hin4[(size_t)(y1 >> 16) * 16 + q];
            uintx4 hy2 = Hin4[(size_t)(y2 >> 16) * 16 + q];
            uintx4 hy3 = Hin4[(size_t)(y3 >> 16) * 16 + q];
            float vx0 = __uint_as_float(x0 << 16);
            float vx1 = __uint_as_float(x1 << 16);
            float vx2 = __uint_as_float(x2 << 16);
            float vx3 = __uint_as_float(x3 << 16);
            float vy0 = __uint_as_float(y0 << 16);
            float vy1 = __uint_as_float(y1 << 16);
            float vy2 = __uint_as_float(y2 << 16);
            float vy3 = __uint_as_float(y3 << 16);
            FMA8(a0, vx0, hx0);
            FMA8(a0, vx1, hx1);
            FMA8(a0, vx2, hx2);
            FMA8(a0, vx3, hx3);
            FMA8(a1, vy0, hy0);
            FMA8(a1, vy1, hy1);
            FMA8(a1, vy2, hy2);
            FMA8(a1, vy3, hy3);
        }
        b0 += 64;
        b1 += 64;
    }
    // reduce the 4 edge-subsets (lane bits 4..5)
    #pragma unroll
    for (int i = 0; i < 8; ++i) {
        a0[i] += __shfl_xor(a0[i], 16);
        a0[i] += __shfl_xor(a0[i], 32);
        a1[i] += __shfl_xor(a1[i], 16);
        a1[i] += __shfl_xor(a1[i], 32);
    }
    if (p == 0) {
        spmm_store<MODE>(pr,     a0, q, Hout4, feats, h1b4, h2b4);
        spmm_store<MODE>(pr + 1, a1, q, Hout4, feats, h1b4, h2b4);
    }
}

// ---------------- fused MLP v2: B-frags direct from L2, LDS only for H1 transpose ----------
// One block = 64 rows, 4 waves; wave w owns rows w*16..w*16+15 for BOTH gemms, so the
// h1u tile is written and read by the SAME wave only -> no barrier needed (within-wave
// DS ordering suffices).
#define H1_STRIDE 264   // ushorts per row (132 u32)
__global__ __launch_bounds__(256) void mlp_fused(const uint4* __restrict__ yb4,
                                                 const uint4* __restrict__ W1frag,
                                                 const uint4* __restrict__ W2frag,
                                                 const float* __restrict__ bias1,
                                                 const float* __restrict__ b2,
                                                 float* __restrict__ Out) {
    __shared__ unsigned short h1u[64 * H1_STRIDE];    // 33 KB: H1 tile, bf16
    int tid = threadIdx.x;
    int w = tid >> 6, lane = tid & 63;
    int q = lane >> 4, c16 = lane & 15;
    int row0 = blockIdx.x * 64;
    int arow = row0 + w * 16 + c16;

    union { uint4 u; short8 v; } au[4], bu, af;
    if (arow < N_NODES) {
        #pragma unroll
        for (int s = 0; s < 4; ++s)
            au[s].u = yb4[(size_t)arow * 16 + 4 * s + q];
    } else {
        #pragma unroll
        for (int s = 0; s < 4; ++s)
            au[s].u = make_uint4(0u, 0u, 0u, 0u);
    }

    // ---- gemm1: 16 col-tiles, B-frags straight from L2 ----
    #pragma unroll 4
    for (int ct = 0; ct < 16; ++ct) {
        floatx4 acc = {0.f, 0.f, 0.f, 0.f};
        #pragma unroll
        for (int s = 0; s < 4; ++s) {
            bu.u = W1frag[(ct * 4 + s) * 64 + lane];
            acc = __builtin_amdgcn_mfma_f32_16x16x32_bf16(au[s].v, bu.v, acc, 0, 0, 0);
        }
        int col = ct * 16 + c16;
        float bs = bias1[col];
        #pragma unroll
        for (int r = 0; r < 4; ++r) {
            float v = 0.25f * acc[r] + bs;
            v = v > 0.f ? v : 0.f;
            h1u[(w * 16 + q * 4 + r) * H1_STRIDE + col] = (unsigned short)bf16bits(v);
        }
    }
    // no barrier: wave w reads only its own rows of h1u

    // ---- gemm2: wave w owns row-tile w; B-frags straight from L2 ----
    floatx4 acc2[3] = {{0.f,0.f,0.f,0.f},{0.f,0.f,0.f,0.f},{0.f,0.f,0.f,0.f}};
    const unsigned* h1w = (const unsigned*)h1u;
    #pragma unroll
    for (int ks = 0; ks < 8; ++ks) {
        af.u = *(const uint4*)&h1w[(w * 16 + c16) * (H1_STRIDE / 2) + ks * 16 + q * 4];
        #pragma unroll
        for (int nt = 0; nt < 3; ++nt) {
            bu.u = W2frag[nt * 512 + ks * 64 + lane];
            acc2[nt] = __builtin_amdgcn_mfma_f32_16x16x32_bf16(af.v, bu.v, acc2[nt], 0, 0, 0);
        }
    }

    // ---- +b2, double log_softmax (rows span 16-lane groups), write ----
    float bb[3];
    #pragma unroll
    for (int nt = 0; nt < 3; ++nt) {
        int col = nt * 16 + c16;
        bb[nt] = (col < NCLASS) ? b2[col] : 0.f;
    }
    #pragma unroll
    for (int r = 0; r < 4; ++r) {
        int gr = row0 + w * 16 + q * 4 + r;
        float z[3];
        #pragma unroll
        for (int nt = 0; nt < 3; ++nt) z[nt] = acc2[nt][r] + bb[nt];
        if (c16 >= 8) z[2] = -INFINITY;   // cols 40..47 are padding
        float m = fmaxf(fmaxf(z[0], z[1]), z[2]);
        #pragma unroll
        for (int off = 1; off < 16; off <<= 1) m = fmaxf(m, __shfl_xor(m, off));
        float s = expf(z[0] - m) + expf(z[1] - m) + ((c16 < 8) ? expf(z[2] - m) : 0.f);
        #pragma unroll
        for (int off = 1; off < 16; off <<= 1) s += __shfl_xor(s, off);
        float l1 = m + logf(s);
        #pragma unroll
        for (int nt = 0; nt < 3; ++nt) z[nt] -= l1;
        float m2 = fmaxf(fmaxf(z[0], z[1]), z[2]);
        #pragma unroll
        for (int off = 1; off < 16; off <<= 1) m2 = fmaxf(m2, __shfl_xor(m2, off));
        float s2 = expf(z[0] - m2) + expf(z[1] - m2) + ((c16 < 8) ? expf(z[2] - m2) : 0.f);
        #pragma unroll
        for (int off = 1; off < 16; off <<= 1) s2 += __shfl_xor(s2, off);
        float l2 = m2 + logf(s2);
        if (gr < N_NODES) {
            #pragma unroll
            for (int nt = 0; nt < 3; ++nt) {
                int col = nt * 16 + c16;
                if (col < NCLASS)
                    Out[(size_t)gr * NCLASS + col] = z[nt] - l2;
            }
        }
    }
}

extern "C" void kernel_launch(void* const* d_in, const int* in_sizes, int n_in,
                              void* d_out, int out_size, void* d_ws, size_t ws_size,
                              hipStream_t stream) {
    const float* feats   = (const float*)d_in[0];
    const int*   e_row   = (const int*)d_in[1];
    const int*   e_col   = (const int*)d_in[2];
    const float* e_vals  = (const float*)d_in[3];
    const float* W1      = (const float*)d_in[4];
    const float* b1      = (const float*)d_in[5];
    const float* W2      = (const float*)d_in[6];
    const float* b2      = (const float*)d_in[7];
    float* out = (float*)d_out;

    // Workspace (19.2M floats proven):
    //   hist  : [0, 3.2M)           256 x 12500 packed u32 (12.8 MB; dead after colscan)
    //   ybf   : [0, 3.2M)           y in bf16 (MLP input, written by hop3)
    //   W1frag: [3.2M, 3.217M)      W1 bf16 MFMA fragments (64 KB)
    //   W2frag: [3.25M, 3.257M)     W2 bf16 MFMA fragments (24 KB)
    //   counts: [3.3M, 3.35M)       per-row degrees (dead after local_scan)
    //   goff  : [3.4M, 3.45M)       colscan group offsets (dead after scatter)
    //   fb16  : [6.4M, 9.6M)        feats in bf16
    //   h1b   : [9.6M, 12.8M)       hop1 out, bf16
    //   h2b   : [12.8M, 16M)        hop2 out, bf16
    //   base  : [16M, 19.2M)        per-(block,row) packed bases (dead after scatter)
    float* ws    = (float*)d_ws;
    uint4* ybf4  = (uint4*)ws;
    unsigned* hist = (unsigned*)ws;
    uint4* W1frag = (uint4*)(ws + (size_t)N_NODES * IN_DIM / 2);
    uint4* W2frag = (uint4*)(ws + 3250000);
    int*   counts = (int*)(ws + 3300000);
    unsigned* goff = (unsigned*)(ws + 3400000);
    uint4* fb16_4 = (uint4*)(ws + (size_t)N_NODES * IN_DIM);
    uint4* h1b4  = (uint4*)(ws + (size_t)N_NODES * IN_DIM * 3 / 2);
    uint4* h2b4  = (uint4*)(ws + (size_t)N_NODES * IN_DIM * 2);
    unsigned* basep = (unsigned*)(ws + (size_t)N_NODES * IN_DIM * 5 / 2);   // 16M..19.2M

    // CSR scratch in d_out (8 MB; fully overwritten by mlp_fused at the end).
    unsigned* csr_cv = (unsigned*)d_out;                 // packed (col<<16)|bf16(val), 800000
    int*   row_start = (int*)d_out + 2 * N_EDGES;        // [1600000, 1650001)
    int*   blockSums = row_start + N_NODES + 4;          // < 2000000

    // fused prep + hist: feats->bf16, W1/W2 frag pack, privatized LDS histograms
    prep_hist_kernel<<<HBLK, 1024, 0, stream>>>((const float4*)feats, (uint2*)fb16_4,
                                                W1, W1frag, W2, W2frag, e_row, hist);

    // CSR build, zero global atomics
    colscan_kernel<<<SCAN_NBLK, 1024, 0, stream>>>(hist, basep, goff, counts, blockSums);
    local_scan_kernel<<<SCAN_NBLK, 256, 0, stream>>>(counts, blockSums, row_start);
    scatter2_kernel<<<HBLK, 1024, 0, stream>>>(e_row, e_col, e_vals, basep, goff,
                                               row_start, csr_cv);

    // 3 propagation hops (2 rows/wave, dual 4-gather chains: 8 gathers in flight)
    const int SPMM_BLOCKS = N_NODES / 8;      // 6250 (4 waves/block, 2 rows/wave)
    spmm_csr<1><<<SPMM_BLOCKS, 256, 0, stream>>>(row_start, csr_cv, (const uintx4*)fb16_4,
                                                 (uintx4*)h1b4, nullptr, nullptr, nullptr);
    spmm_csr<0><<<SPMM_BLOCKS, 256, 0, stream>>>(row_start, csr_cv, (const uintx4*)h1b4,
                                                 (uintx4*)h2b4, nullptr, nullptr, nullptr);
    spmm_csr<2><<<SPMM_BLOCKS, 256, 0, stream>>>(row_start, csr_cv, (const uintx4*)h2b4,
                                                 (uintx4*)ybf4, feats,
                                                 (const uintx4*)h1b4, (const uintx4*)h2b4);

    // fused MLP v2: relu(0.25*(ybf@W1)+b1) @ W2 + b2 -> double log_softmax -> out
    mlp_fused<<<(N_NODES + 63) / 64, 256, 0, stream>>>(ybf4, W1frag, W2frag, b1, b2, out);
}

// Round 8
// 225.962 us; speedup vs baseline: 1.0512x; 1.0512x over previous
//
#include <hip/hip_runtime.h>
#include <math.h>

#define N_NODES 50000
#define N_EDGES 800000
#define IN_DIM 128
#define HID 256
#define NCLASS 40

#define SCAN_NBLK 49   // ceil(50000 / 1024)

// CSR build: 256 privatized histogram blocks, 8-bit packed counters (4 rows/u32)
#define HBLK 256
#define EPB  3125      // edges per hist block: 256 * 3125 = 800000 exactly
#define PK   12500     // packed u32 bins (50000 rows / 4)
#define CS_G 4         // colscan hist groups
#define CS_HPG 64      // hists per group (256/4)

typedef __attribute__((ext_vector_type(8))) short short8;
typedef __attribute__((ext_vector_type(4))) float floatx4;
typedef __attribute__((ext_vector_type(4))) unsigned uintx4;

// ---------- bf16 helpers (RNE pack, cheap unpack) ----------
__device__ inline unsigned bf16pair(float a, float b) {
    unsigned ua = __float_as_uint(a), ub = __float_as_uint(b);
    ua = (ua + 0x7fffu + ((ua >> 16) & 1u)) >> 16;
    ub = (ub + 0x7fffu + ((ub >> 16) & 1u)) >> 16;
    return ua | (ub << 16);
}
__device__ inline unsigned bf16bits(float a) {
    unsigned ua = __float_as_uint(a);
    return (ua + 0x7fffu + ((ua >> 16) & 1u)) >> 16;
}
__device__ inline float bf_lo(unsigned u) { return __uint_as_float(u << 16); }
__device__ inline float bf_hi(unsigned u) { return __uint_as_float(u & 0xffff0000u); }

#define FMA8(A, v, h) do { \
    A[0] += (v) * bf_lo((h).x); A[1] += (v) * bf_hi((h).x); \
    A[2] += (v) * bf_lo((h).y); A[3] += (v) * bf_hi((h).y); \
    A[4] += (v) * bf_lo((h).z); A[5] += (v) * bf_hi((h).z); \
    A[6] += (v) * bf_lo((h).w); A[7] += (v) * bf_hi((h).w); } while (0)

// ---------------- fused prep + hist ----------------
// 256 blocks x 1024: per-block privatized LDS histogram (8-bit packed; degree < 256),
// plus grid-stride feats->bf16 conversion and W1/W2 MFMA fragment packing.
__global__ __launch_bounds__(1024) void prep_hist_kernel(const float4* __restrict__ f4,
                                                         uint2* __restrict__ fb16,
                                                         const float* __restrict__ W1,
                                                         uint4* __restrict__ W1frag,
                                                         const float* __restrict__ W2,
                                                         uint4* __restrict__ W2frag,
                                                         const int* __restrict__ rows,
                                                         unsigned* __restrict__ hist) {
    __shared__ unsigned h[PK];    // 50 KB
    int t = threadIdx.x;
    for (int i = t; i < PK / 4; i += 1024)
        ((uint4*)h)[i] = make_uint4(0u, 0u, 0u, 0u);
    __syncthreads();
    int e0 = blockIdx.x * EPB;
    for (int i = t; i < EPB; i += 1024) {
        int r = rows[e0 + i];
        atomicAdd(&h[r >> 2], 1u << ((r & 3) * 8));   // LDS atomic
    }
    // streaming prep (overlaps atomic settle; no sync needed before it)
    int gid = blockIdx.x * 1024 + t;                  // < 262144
    for (int i = gid; i < N_NODES * IN_DIM / 4; i += HBLK * 1024) {
        float4 v = f4[i];
        fb16[i] = make_uint2(bf16pair(v.x, v.y), bf16pair(v.z, v.w));
    }
    if (gid < 4096) {
        int f = gid;
        int hh = f >> 11, rem = f & 2047;
        int tt = rem >> 8, s = (rem >> 6) & 3, l = rem & 63;
        int q = l >> 4, n16 = l & 15;
        int n = hh * 128 + tt * 16 + n16;
        int kb = s * 32 + q * 8;
        unsigned p[4];
        #pragma unroll
        for (int jj = 0; jj < 4; ++jj) {
            float a = W1[(size_t)(kb + 2 * jj) * HID + n];
            float b = W1[(size_t)(kb + 2 * jj + 1) * HID + n];
            p[jj] = bf16pair(a, b);
        }
        W1frag[f] = make_uint4(p[0], p[1], p[2], p[3]);
    } else if (gid < 4096 + 1536) {
        // W2 B-fragments: [nt(3)][ks(8)][lane(64)], cols padded 40->48 with zeros
        int f2 = gid - 4096;
        int nt = f2 >> 9;
        int rem = f2 & 511;
        int ks = rem >> 6, l = rem & 63;
        int col = nt * 16 + (l & 15);
        int k = ks * 32 + (l >> 4) * 8;
        unsigned p[4];
        #pragma unroll
        for (int jj = 0; jj < 4; ++jj) {
            float a = (col < NCLASS) ? W2[(size_t)(k + 2 * jj) * NCLASS + col] : 0.f;
            float b = (col < NCLASS) ? W2[(size_t)(k + 2 * jj + 1) * NCLASS + col] : 0.f;
            p[jj] = bf16pair(a, b);
        }
        W2frag[f2] = make_uint4(p[0], p[1], p[2], p[3]);
    }
    __syncthreads();
    unsigned* out = hist + (size_t)blockIdx.x * PK;
    for (int i = t; i < PK / 4; i += 1024)
        ((uint4*)out)[i] = ((const uint4*)h)[i];
}

// ---------------- colscan v2: 4-way parallel per-row prefix across 256 block-histograms ----
__global__ __launch_bounds__(1024) void colscan_kernel(const unsigned* __restrict__ hist,
                                                       unsigned* __restrict__ base,
                                                       unsigned* __restrict__ goff,
                                                       int* __restrict__ counts,
                                                       int* __restrict__ blockSums) {
    __shared__ unsigned lsum[CS_G][256];
    int tid = threadIdx.x;          // 1024
    int g = tid >> 8;               // 0..3 hist group
    int c = tid & 255;              // col-quad within block
    int colq = blockIdx.x * 256 + c;
    unsigned run = 0;               // 4 packed 8-bit running sums (degree < 256: no overflow)
    if (colq < PK) {
        #pragma unroll 8
        for (int i = 0; i < CS_HPG; ++i) {
            int b = g * CS_HPG + i;
            unsigned v = hist[(size_t)b * PK + colq];
            base[(size_t)b * PK + colq] = run;
            run += v;
        }
    }
    lsum[g][c] = run;
    __syncthreads();
    unsigned off = 0;
    #pragma unroll
    for (int gg = 0; gg < CS_G; ++gg) {
        unsigned v = lsum[gg][c];
        if (gg < g) off += v;
    }
    unsigned tot = off + run;       // valid for g == CS_G-1: full per-row degrees (packed)
    if (colq < PK) {
        goff[(size_t)g * PK + colq] = off;
        if (g == CS_G - 1)
            *(int4*)(counts + 4 * colq) = make_int4((int)(tot & 0xffu), (int)((tot >> 8) & 0xffu),
                                                    (int)((tot >> 16) & 0xffu), (int)(tot >> 24));
    }
    // per-scanblock edge-count sum (rows [blk*1024, blk*1024+1024))
    int s = 0;
    if (g == CS_G - 1 && colq < PK)
        s = (int)((tot & 0xffu) + ((tot >> 8) & 0xffu) + ((tot >> 16) & 0xffu) + (tot >> 24));
    #pragma unroll
    for (int o = 32; o >= 1; o >>= 1)
        s += __shfl_xor(s, o);
    __shared__ int wsum[16];
    int lane = tid & 63, wid = tid >> 6;
    if (lane == 0) wsum[wid] = s;
    __syncthreads();
    if (tid == 0) {
        int acc = 0;
        #pragma unroll
        for (int i = 0; i < 16; ++i) acc += wsum[i];
        blockSums[blockIdx.x] = acc;
    }
}

// ---------------- local scan (fused block-offset scan) -> row_start ----------------
// NOTE: 256 threads exactly (t*4 covers this block's 1024 rows; wsum sized for 4 waves).
__global__ __launch_bounds__(256) void local_scan_kernel(const int* __restrict__ counts,
                                                         const int* __restrict__ blockSums,
                                                         int* __restrict__ row_start) {
    __shared__ int wsum[4];
    __shared__ int boff;
    int t = threadIdx.x;
    // wave 0: scan the 49 block sums; every block computes its own offset
    if (t < 64) {
        int x = (t < SCAN_NBLK) ? blockSums[t] : 0;
        #pragma unroll
        for (int off = 1; off < 64; off <<= 1) {
            int y = __shfl_up(x, off);
            if (t >= off) x += y;
        }
        int excl = __shfl_up(x, 1);
        if (t == 0) excl = 0;
        if (t == blockIdx.x) boff = excl;
        if (blockIdx.x == SCAN_NBLK - 1 && t == SCAN_NBLK - 1)
            row_start[N_NODES] = x;   // grand total
    }
    int base = blockIdx.x * 1024 + t * 4;
    int4 c = make_int4(0, 0, 0, 0);
    if (base < N_NODES) c = *(const int4*)(counts + base);
    int s0 = c.x, s1 = s0 + c.y, s2 = s1 + c.z, s3 = s2 + c.w;
    int tsum = s3;
    int lane = t & 63, wid = t >> 6;
    int x = tsum;
    #pragma unroll
    for (int off = 1; off < 64; off <<= 1) {
        int y = __shfl_up(x, off);
        if (lane >= off) x += y;
    }
    if (lane == 63) wsum[wid] = x;
    __syncthreads();
    int woff = 0;
    for (int i = 0; i < 4; ++i)
        if (i < wid) woff += wsum[i];
    int excl = x - tsum + woff + boff;
    if (base < N_NODES) {
        int4 rs = make_int4(excl, excl + s0, excl + s1, excl + s2);
        *(int4*)(row_start + base) = rs;
    }
}

// ---------------- scatter2: rank via LDS atomic replay (zero global atomics) ----------------
__global__ __launch_bounds__(1024) void scatter2_kernel(const int* __restrict__ rows,
                                                        const int* __restrict__ cols,
                                                        const float* __restrict__ vals,
                                                        const unsigned* __restrict__ base,
                                                        const unsigned* __restrict__ goff,
                                                        const int* __restrict__ row_start,
                                                        unsigned* __restrict__ csr_cv) {
    __shared__ unsigned cur[PK];  // 50 KB: this block's packed per-row bases
    int t = threadIdx.x;
    const uint4* bb = (const uint4*)(base + (size_t)blockIdx.x * PK);
    const uint4* gg = (const uint4*)(goff + (size_t)(blockIdx.x >> 6) * PK);
    for (int i = t; i < PK / 4; i += 1024) {
        uint4 b = bb[i], o = gg[i];
        // byte-parallel add: per-row sums < 256 so no cross-byte carries
        ((uint4*)cur)[i] = make_uint4(b.x + o.x, b.y + o.y, b.z + o.z, b.w + o.w);
    }
    __syncthreads();
    int e0 = blockIdx.x * EPB;
    for (int i = t; i < EPB; i += 1024) {
        int e = e0 + i;
        int r = rows[e];
        unsigned sh = (unsigned)(r & 3) * 8u;
        unsigned old = atomicAdd(&cur[r >> 2], 1u << sh);   // LDS atomic
        int pos = row_start[r] + (int)((old >> sh) & 0xffu);
        csr_cv[pos] = ((unsigned)cols[e] << 16) | bf16bits(vals[e]);
    }
}

// ---------------- SpMM (CSR, quarter-wave per edge, 16-edge unrolled gathers) ----------------
// lane = 16p+q: p = edge-of-quad, q = dim group of 8 (one 16B chunk of the row).
// Inner loop handles 16 edges (4 quads) per iteration: FOUR independent dwordx4
// gathers in flight per lane. Zero-padding beyond cnt (u=0 -> col 0, val +0.0)
// makes over-run exact; pad gathers broadcast row 0 (L1 hit).
// NOTE: Hout store is a NORMAL cached store — it is the NEXT hop's gather source
// (and mlp's input); nontemporal stores would evict it from L2/L3 and push the
// next hop's random gathers out to HBM distance. Only true streaming reads keep nt.
// MODE 0: Hout[r] = bf16(acc)                               (hop 2)
// MODE 1: Hout[r] = bf16(0.5*acc)                           (hop 1, folds input scale)
// MODE 2: Hout[r] = bf16(0.5*feats[r] + h1[r] + h2[r] + acc)   (hop 3, y in bf16)
template <int MODE>
__global__ __launch_bounds__(256) void spmm_csr(const int* __restrict__ row_start,
                                                const unsigned* __restrict__ csr_cv,
                                                const uintx4* __restrict__ Hin4,
                                                uintx4* __restrict__ Hout4,
                                                const float* __restrict__ feats,
                                                const uintx4* __restrict__ h1b4,
                                                const uintx4* __restrict__ h2b4) {
    int wave = (blockIdx.x * blockDim.x + threadIdx.x) >> 6;
    int lane = threadIdx.x & 63;
    if (wave >= N_NODES) return;
    int p = lane >> 4;          // 0..3: which edge of the quad
    int q = lane & 15;          // dim group (8 dims = 16 B)
    int start = row_start[wave];
    int end   = row_start[wave + 1];
    float acc[8] = {};
    for (int base = start; base < end; base += 64) {
        int idx = base + lane;
        unsigned u = 0;                         // col=0, val=+0.0 padding
        if (idx < end) u = __builtin_nontemporal_load(csr_cv + idx);
        int cnt = min(64, end - base);
        for (int j = 0; j < cnt; j += 16) {
            unsigned uj0 = __shfl(u, j + p);
            unsigned uj1 = __shfl(u, j + 4 + p);
            unsigned uj2 = __shfl(u, j + 8 + p);
            unsigned uj3 = __shfl(u, j + 12 + p);   // <= 63: ok
            int c0 = uj0 >> 16, c1 = uj1 >> 16, c2 = uj2 >> 16, c3 = uj3 >> 16;
            float v0 = __uint_as_float(uj0 << 16);
            float v1 = __uint_as_float(uj1 << 16);
            float v2 = __uint_as_float(uj2 << 16);
            float v3 = __uint_as_float(uj3 << 16);
            uintx4 h0 = Hin4[(size_t)c0 * 16 + q];   // 4 independent gathers in flight
            uintx4 h1 = Hin4[(size_t)c1 * 16 + q];
            uintx4 h2 = Hin4[(size_t)c2 * 16 + q];
            uintx4 h3 = Hin4[(size_t)c3 * 16 + q];
            FMA8(acc, v0, h0);
            FMA8(acc, v1, h1);
            FMA8(acc, v2, h2);
            FMA8(acc, v3, h3);
        }
    }
    // reduce the 4 edge-subsets (lane bits 4..5)
    #pragma unroll
    for (int i = 0; i < 8; ++i) {
        acc[i] += __shfl_xor(acc[i], 16);
        acc[i] += __shfl_xor(acc[i], 32);
    }
    if (p == 0) {
        size_t o16 = (size_t)wave * 16 + q;
        if (MODE == 1) {
            #pragma unroll
            for (int i = 0; i < 8; ++i) acc[i] *= 0.5f;
        } else if (MODE == 2) {
            size_t of = (size_t)wave * IN_DIM + q * 8;
            floatx4 f0 = __builtin_nontemporal_load((const floatx4*)(feats + of));
            floatx4 f1 = __builtin_nontemporal_load((const floatx4*)(feats + of + 4));
            uintx4 a = __builtin_nontemporal_load(h1b4 + o16);
            uintx4 b = __builtin_nontemporal_load(h2b4 + o16);
            acc[0] += 0.5f * f0.x + bf_lo(a.x) + bf_lo(b.x);
            acc[1] += 0.5f * f0.y + bf_hi(a.x) + bf_hi(b.x);
            acc[2] += 0.5f * f0.z + bf_lo(a.y) + bf_lo(b.y);
            acc[3] += 0.5f * f0.w + bf_hi(a.y) + bf_hi(b.y);
            acc[4] += 0.5f * f1.x + bf_lo(a.z) + bf_lo(b.z);
            acc[5] += 0.5f * f1.y + bf_hi(a.z) + bf_hi(b.z);
            acc[6] += 0.5f * f1.z + bf_lo(a.w) + bf_lo(b.w);
            acc[7] += 0.5f * f1.w + bf_hi(a.w) + bf_hi(b.w);
        }
        uintx4 rv;
        rv.x = bf16pair(acc[0], acc[1]);
        rv.y = bf16pair(acc[2], acc[3]);
        rv.z = bf16pair(acc[4], acc[5]);
        rv.w = bf16pair(acc[6], acc[7]);
        Hout4[o16] = rv;          // cached store: next hop gathers from this buffer
    }
}

// ---------------- fused MLP v2: B-frags direct from L2, LDS only for H1 transpose ----------
// One block = 64 rows, 4 waves; wave w owns rows w*16..w*16+15 for BOTH gemms, so the
// h1u tile is written and read by the SAME wave only -> no barrier needed (within-wave
// DS ordering suffices).
#define H1_STRIDE 264   // ushorts per row (132 u32)
__global__ __launch_bounds__(256) void mlp_fused(const uint4* __restrict__ yb4,
                                                 const uint4* __restrict__ W1frag,
                                                 const uint4* __restrict__ W2frag,
                                                 const float* __restrict__ bias1,
                                                 const float* __restrict__ b2,
                                                 float* __restrict__ Out) {
    __shared__ unsigned short h1u[64 * H1_STRIDE];    // 33 KB: H1 tile, bf16
    int tid = threadIdx.x;
    int w = tid >> 6, lane = tid & 63;
    int q = lane >> 4, c16 = lane & 15;
    int row0 = blockIdx.x * 64;
    int arow = row0 + w * 16 + c16;

    union { uint4 u; short8 v; } au[4], bu, af;
    if (arow < N_NODES) {
        #pragma unroll
        for (int s = 0; s < 4; ++s)
            au[s].u = yb4[(size_t)arow * 16 + 4 * s + q];
    } else {
        #pragma unroll
        for (int s = 0; s < 4; ++s)
            au[s].u = make_uint4(0u, 0u, 0u, 0u);
    }

    // ---- gemm1: 16 col-tiles, B-frags straight from L2 ----
    #pragma unroll 4
    for (int ct = 0; ct < 16; ++ct) {
        floatx4 acc = {0.f, 0.f, 0.f, 0.f};
        #pragma unroll
        for (int s = 0; s < 4; ++s) {
            bu.u = W1frag[(ct * 4 + s) * 64 + lane];
            acc = __builtin_amdgcn_mfma_f32_16x16x32_bf16(au[s].v, bu.v, acc, 0, 0, 0);
        }
        int col = ct * 16 + c16;
        float bs = bias1[col];
        #pragma unroll
        for (int r = 0; r < 4; ++r) {
            float v = 0.25f * acc[r] + bs;
            v = v > 0.f ? v : 0.f;
            h1u[(w * 16 + q * 4 + r) * H1_STRIDE + col] = (unsigned short)bf16bits(v);
        }
    }
    // no barrier: wave w reads only its own rows of h1u

    // ---- gemm2: wave w owns row-tile w; B-frags straight from L2 ----
    floatx4 acc2[3] = {{0.f,0.f,0.f,0.f},{0.f,0.f,0.f,0.f},{0.f,0.f,0.f,0.f}};
    const unsigned* h1w = (const unsigned*)h1u;
    #pragma unroll
    for (int ks = 0; ks < 8; ++ks) {
        af.u = *(const uint4*)&h1w[(w * 16 + c16) * (H1_STRIDE / 2) + ks * 16 + q * 4];
        #pragma unroll
        for (int nt = 0; nt < 3; ++nt) {
            bu.u = W2frag[nt * 512 + ks * 64 + lane];
            acc2[nt] = __builtin_amdgcn_mfma_f32_16x16x32_bf16(af.v, bu.v, acc2[nt], 0, 0, 0);
        }
    }

    // ---- +b2, double log_softmax (rows span 16-lane groups), write ----
    float bb[3];
    #pragma unroll
    for (int nt = 0; nt < 3; ++nt) {
        int col = nt * 16 + c16;
        bb[nt] = (col < NCLASS) ? b2[col] : 0.f;
    }
    #pragma unroll
    for (int r = 0; r < 4; ++r) {
        int gr = row0 + w * 16 + q * 4 + r;
        float z[3];
        #pragma unroll
        for (int nt = 0; nt < 3; ++nt) z[nt] = acc2[nt][r] + bb[nt];
        if (c16 >= 8) z[2] = -INFINITY;   // cols 40..47 are padding
        float m = fmaxf(fmaxf(z[0], z[1]), z[2]);
        #pragma unroll
        for (int off = 1; off < 16; off <<= 1) m = fmaxf(m, __shfl_xor(m, off));
        float s = expf(z[0] - m) + expf(z[1] - m) + ((c16 < 8) ? expf(z[2] - m) : 0.f);
        #pragma unroll
        for (int off = 1; off < 16; off <<= 1) s += __shfl_xor(s, off);
        float l1 = m + logf(s);
        #pragma unroll
        for (int nt = 0; nt < 3; ++nt) z[nt] -= l1;
        float m2 = fmaxf(fmaxf(z[0], z[1]), z[2]);
        #pragma unroll
        for (int off = 1; off < 16; off <<= 1) m2 = fmaxf(m2, __shfl_xor(m2, off));
        float s2 = expf(z[0] - m2) + expf(z[1] - m2) + ((c16 < 8) ? expf(z[2] - m2) : 0.f);
        #pragma unroll
        for (int off = 1; off < 16; off <<= 1) s2 += __shfl_xor(s2, off);
        float l2 = m2 + logf(s2);
        if (gr < N_NODES) {
            #pragma unroll
            for (int nt = 0; nt < 3; ++nt) {
                int col = nt * 16 + c16;
                if (col < NCLASS)
                    Out[(size_t)gr * NCLASS + col] = z[nt] - l2;
            }
        }
    }
}

extern "C" void kernel_launch(void* const* d_in, const int* in_sizes, int n_in,
                              void* d_out, int out_size, void* d_ws, size_t ws_size,
                              hipStream_t stream) {
    const float* feats   = (const float*)d_in[0];
    const int*   e_row   = (const int*)d_in[1];
    const int*   e_col   = (const int*)d_in[2];
    const float* e_vals  = (const float*)d_in[3];
    const float* W1      = (const float*)d_in[4];
    const float* b1      = (const float*)d_in[5];
    const float* W2      = (const float*)d_in[6];
    const float* b2      = (const float*)d_in[7];
    float* out = (float*)d_out;

    // Workspace (19.2M floats proven):
    //   hist  : [0, 3.2M)           256 x 12500 packed u32 (12.8 MB; dead after colscan)
    //   ybf   : [0, 3.2M)           y in bf16 (MLP input, written by hop3)
    //   W1frag: [3.2M, 3.217M)      W1 bf16 MFMA fragments (64 KB)
    //   W2frag: [3.25M, 3.257M)     W2 bf16 MFMA fragments (24 KB)
    //   counts: [3.3M, 3.35M)       per-row degrees (dead after local_scan)
    //   goff  : [3.4M, 3.45M)       colscan group offsets (dead after scatter)
    //   fb16  : [6.4M, 9.6M)        feats in bf16
    //   h1b   : [9.6M, 12.8M)       hop1 out, bf16
    //   h2b   : [12.8M, 16M)        hop2 out, bf16
    //   base  : [16M, 19.2M)        per-(block,row) packed bases (dead after scatter)
    float* ws    = (float*)d_ws;
    uint4* ybf4  = (uint4*)ws;
    unsigned* hist = (unsigned*)ws;
    uint4* W1frag = (uint4*)(ws + (size_t)N_NODES * IN_DIM / 2);
    uint4* W2frag = (uint4*)(ws + 3250000);
    int*   counts = (int*)(ws + 3300000);
    unsigned* goff = (unsigned*)(ws + 3400000);
    uint4* fb16_4 = (uint4*)(ws + (size_t)N_NODES * IN_DIM);
    uint4* h1b4  = (uint4*)(ws + (size_t)N_NODES * IN_DIM * 3 / 2);
    uint4* h2b4  = (uint4*)(ws + (size_t)N_NODES * IN_DIM * 2);
    unsigned* basep = (unsigned*)(ws + (size_t)N_NODES * IN_DIM * 5 / 2);   // 16M..19.2M

    // CSR scratch in d_out (8 MB; fully overwritten by mlp_fused at the end).
    unsigned* csr_cv = (unsigned*)d_out;                 // packed (col<<16)|bf16(val), 800000
    int*   row_start = (int*)d_out + 2 * N_EDGES;        // [1600000, 1650001)
    int*   blockSums = row_start + N_NODES + 4;          // < 2000000

    // fused prep + hist: feats->bf16, W1/W2 frag pack, privatized LDS histograms
    prep_hist_kernel<<<HBLK, 1024, 0, stream>>>((const float4*)feats, (uint2*)fb16_4,
                                                W1, W1frag, W2, W2frag, e_row, hist);

    // CSR build, zero global atomics
    colscan_kernel<<<SCAN_NBLK, 1024, 0, stream>>>(hist, basep, goff, counts, blockSums);
    local_scan_kernel<<<SCAN_NBLK, 256, 0, stream>>>(counts, blockSums, row_start);
    scatter2_kernel<<<HBLK, 1024, 0, stream>>>(e_row, e_col, e_vals, basep, goff,
                                               row_start, csr_cv);

    // 3 propagation hops (quarter-wave per edge, 16-edge unrolled: 4 gathers in flight)
    const int SPMM_BLOCKS = N_NODES / 4;      // 12500 (4 waves/block)
    spmm_csr<1><<<SPMM_BLOCKS, 256, 0, stream>>>(row_start, csr_cv, (const uintx4*)fb16_4,
                                                 (uintx4*)h1b4, nullptr, nullptr, nullptr);
    spmm_csr<0><<<SPMM_BLOCKS, 256, 0, stream>>>(row_start, csr_cv, (const uintx4*)h1b4,
                                                 (uintx4*)h2b4, nullptr, nullptr, nullptr);
    spmm_csr<2><<<SPMM_BLOCKS, 256, 0, stream>>>(row_start, csr_cv, (const uintx4*)h2b4,
                                                 (uintx4*)ybf4, feats,
                                                 (const uintx4*)h1b4, (const uintx4*)h2b4);

    // fused MLP v2: relu(0.25*(ybf@W1)+b1) @ W2 + b2 -> double log_softmax -> out
    mlp_fused<<<(N_NODES + 63) / 64, 256, 0, stream>>>(ybf4, W1frag, W2frag, b1, b2, out);
}

// Round 9
// 224.450 us; speedup vs baseline: 1.0583x; 1.0067x over previous
//
#include <hip/hip_runtime.h>
#include <math.h>

#define N_NODES 50000
#define N_EDGES 800000
#define IN_DIM 128
#define HID 256
#define NCLASS 40

#define SCAN_NBLK 49   // ceil(50000 / 1024)

// CSR build: 256 privatized histogram blocks, 8-bit packed counters (4 rows/u32)
#define HBLK 256
#define EPB  3125      // edges per hist block: 256 * 3125 = 800000 exactly
#define PK   12500     // packed u32 bins (50000 rows / 4)
#define CS_G 4         // colscan hist groups
#define CS_HPG 64      // hists per group (256/4)

typedef __attribute__((ext_vector_type(8))) short short8;
typedef __attribute__((ext_vector_type(4))) float floatx4;
typedef __attribute__((ext_vector_type(4))) unsigned uintx4;

// ---------- bf16 helpers (RNE pack, cheap unpack) ----------
__device__ inline unsigned bf16pair(float a, float b) {
    unsigned ua = __float_as_uint(a), ub = __float_as_uint(b);
    ua = (ua + 0x7fffu + ((ua >> 16) & 1u)) >> 16;
    ub = (ub + 0x7fffu + ((ub >> 16) & 1u)) >> 16;
    return ua | (ub << 16);
}
__device__ inline unsigned bf16bits(float a) {
    unsigned ua = __float_as_uint(a);
    return (ua + 0x7fffu + ((ua >> 16) & 1u)) >> 16;
}
__device__ inline float bf_lo(unsigned u) { return __uint_as_float(u << 16); }
__device__ inline float bf_hi(unsigned u) { return __uint_as_float(u & 0xffff0000u); }

#define FMA8(A, v, h) do { \
    A[0] += (v) * bf_lo((h).x); A[1] += (v) * bf_hi((h).x); \
    A[2] += (v) * bf_lo((h).y); A[3] += (v) * bf_hi((h).y); \
    A[4] += (v) * bf_lo((h).z); A[5] += (v) * bf_hi((h).z); \
    A[6] += (v) * bf_lo((h).w); A[7] += (v) * bf_hi((h).w); } while (0)

// ---------------- fused prep + hist ----------------
// 256 blocks x 1024: per-block privatized LDS histogram (8-bit packed; degree < 256),
// plus grid-stride feats->bf16 conversion and W1/W2 MFMA fragment packing.
__global__ __launch_bounds__(1024) void prep_hist_kernel(const float4* __restrict__ f4,
                                                         uint2* __restrict__ fb16,
                                                         const float* __restrict__ W1,
                                                         uint4* __restrict__ W1frag,
                                                         const float* __restrict__ W2,
                                                         uint4* __restrict__ W2frag,
                                                         const int* __restrict__ rows,
                                                         unsigned* __restrict__ hist) {
    __shared__ unsigned h[PK];    // 50 KB
    int t = threadIdx.x;
    for (int i = t; i < PK / 4; i += 1024)
        ((uint4*)h)[i] = make_uint4(0u, 0u, 0u, 0u);
    __syncthreads();
    int e0 = blockIdx.x * EPB;
    for (int i = t; i < EPB; i += 1024) {
        int r = rows[e0 + i];
        atomicAdd(&h[r >> 2], 1u << ((r & 3) * 8));   // LDS atomic
    }
    // streaming prep (overlaps atomic settle; no sync needed before it)
    int gid = blockIdx.x * 1024 + t;                  // < 262144
    for (int i = gid; i < N_NODES * IN_DIM / 4; i += HBLK * 1024) {
        float4 v = f4[i];
        fb16[i] = make_uint2(bf16pair(v.x, v.y), bf16pair(v.z, v.w));
    }
    if (gid < 4096) {
        int f = gid;
        int hh = f >> 11, rem = f & 2047;
        int tt = rem >> 8, s = (rem >> 6) & 3, l = rem & 63;
        int q = l >> 4, n16 = l & 15;
        int n = hh * 128 + tt * 16 + n16;
        int kb = s * 32 + q * 8;
        unsigned p[4];
        #pragma unroll
        for (int jj = 0; jj < 4; ++jj) {
            float a = W1[(size_t)(kb + 2 * jj) * HID + n];
            float b = W1[(size_t)(kb + 2 * jj + 1) * HID + n];
            p[jj] = bf16pair(a, b);
        }
        W1frag[f] = make_uint4(p[0], p[1], p[2], p[3]);
    } else if (gid < 4096 + 1536) {
        // W2 B-fragments: [nt(3)][ks(8)][lane(64)], cols padded 40->48 with zeros
        int f2 = gid - 4096;
        int nt = f2 >> 9;
        int rem = f2 & 511;
        int ks = rem >> 6, l = rem & 63;
        int col = nt * 16 + (l & 15);
        int k = ks * 32 + (l >> 4) * 8;
        unsigned p[4];
        #pragma unroll
        for (int jj = 0; jj < 4; ++jj) {
            float a = (col < NCLASS) ? W2[(size_t)(k + 2 * jj) * NCLASS + col] : 0.f;
            float b = (col < NCLASS) ? W2[(size_t)(k + 2 * jj + 1) * NCLASS + col] : 0.f;
            p[jj] = bf16pair(a, b);
        }
        W2frag[f2] = make_uint4(p[0], p[1], p[2], p[3]);
    }
    __syncthreads();
    unsigned* out = hist + (size_t)blockIdx.x * PK;
    for (int i = t; i < PK / 4; i += 1024)
        ((uint4*)out)[i] = ((const uint4*)h)[i];
}

// ---------------- colscan v2: 4-way parallel per-row prefix across 256 block-histograms ----
__global__ __launch_bounds__(1024) void colscan_kernel(const unsigned* __restrict__ hist,
                                                       unsigned* __restrict__ base,
                                                       unsigned* __restrict__ goff,
                                                       int* __restrict__ counts,
                                                       int* __restrict__ blockSums) {
    __shared__ unsigned lsum[CS_G][256];
    int tid = threadIdx.x;          // 1024
    int g = tid >> 8;               // 0..3 hist group
    int c = tid & 255;              // col-quad within block
    int colq = blockIdx.x * 256 + c;
    unsigned run = 0;               // 4 packed 8-bit running sums (degree < 256: no overflow)
    if (colq < PK) {
        #pragma unroll 8
        for (int i = 0; i < CS_HPG; ++i) {
            int b = g * CS_HPG + i;
            unsigned v = hist[(size_t)b * PK + colq];
            base[(size_t)b * PK + colq] = run;
            run += v;
        }
    }
    lsum[g][c] = run;
    __syncthreads();
    unsigned off = 0;
    #pragma unroll
    for (int gg = 0; gg < CS_G; ++gg) {
        unsigned v = lsum[gg][c];
        if (gg < g) off += v;
    }
    unsigned tot = off + run;       // valid for g == CS_G-1: full per-row degrees (packed)
    if (colq < PK) {
        goff[(size_t)g * PK + colq] = off;
        if (g == CS_G - 1)
            *(int4*)(counts + 4 * colq) = make_int4((int)(tot & 0xffu), (int)((tot >> 8) & 0xffu),
                                                    (int)((tot >> 16) & 0xffu), (int)(tot >> 24));
    }
    // per-scanblock edge-count sum (rows [blk*1024, blk*1024+1024))
    int s = 0;
    if (g == CS_G - 1 && colq < PK)
        s = (int)((tot & 0xffu) + ((tot >> 8) & 0xffu) + ((tot >> 16) & 0xffu) + (tot >> 24));
    #pragma unroll
    for (int o = 32; o >= 1; o >>= 1)
        s += __shfl_xor(s, o);
    __shared__ int wsum[16];
    int lane = tid & 63, wid = tid >> 6;
    if (lane == 0) wsum[wid] = s;
    __syncthreads();
    if (tid == 0) {
        int acc = 0;
        #pragma unroll
        for (int i = 0; i < 16; ++i) acc += wsum[i];
        blockSums[blockIdx.x] = acc;
    }
}

// ---------------- local scan (fused block-offset scan) -> row_start ----------------
// NOTE: 256 threads exactly (t*4 covers this block's 1024 rows; wsum sized for 4 waves).
__global__ __launch_bounds__(256) void local_scan_kernel(const int* __restrict__ counts,
                                                         const int* __restrict__ blockSums,
                                                         int* __restrict__ row_start) {
    __shared__ int wsum[4];
    __shared__ int boff;
    int t = threadIdx.x;
    // wave 0: scan the 49 block sums; every block computes its own offset
    if (t < 64) {
        int x = (t < SCAN_NBLK) ? blockSums[t] : 0;
        #pragma unroll
        for (int off = 1; off < 64; off <<= 1) {
            int y = __shfl_up(x, off);
            if (t >= off) x += y;
        }
        int excl = __shfl_up(x, 1);
        if (t == 0) excl = 0;
        if (t == blockIdx.x) boff = excl;
        if (blockIdx.x == SCAN_NBLK - 1 && t == SCAN_NBLK - 1)
            row_start[N_NODES] = x;   // grand total
    }
    int base = blockIdx.x * 1024 + t * 4;
    int4 c = make_int4(0, 0, 0, 0);
    if (base < N_NODES) c = *(const int4*)(counts + base);
    int s0 = c.x, s1 = s0 + c.y, s2 = s1 + c.z, s3 = s2 + c.w;
    int tsum = s3;
    int lane = t & 63, wid = t >> 6;
    int x = tsum;
    #pragma unroll
    for (int off = 1; off < 64; off <<= 1) {
        int y = __shfl_up(x, off);
        if (lane >= off) x += y;
    }
    if (lane == 63) wsum[wid] = x;
    __syncthreads();
    int woff = 0;
    for (int i = 0; i < 4; ++i)
        if (i < wid) woff += wsum[i];
    int excl = x - tsum + woff + boff;
    if (base < N_NODES) {
        int4 rs = make_int4(excl, excl + s0, excl + s1, excl + s2);
        *(int4*)(row_start + base) = rs;
    }
}

// ---------------- scatter2: rank via LDS atomic replay (zero global atomics) ----------------
__global__ __launch_bounds__(1024) void scatter2_kernel(const int* __restrict__ rows,
                                                        const int* __restrict__ cols,
                                                        const float* __restrict__ vals,
                                                        const unsigned* __restrict__ base,
                                                        const unsigned* __restrict__ goff,
                                                        const int* __restrict__ row_start,
                                                        unsigned* __restrict__ csr_cv) {
    __shared__ unsigned cur[PK];  // 50 KB: this block's packed per-row bases
    int t = threadIdx.x;
    const uint4* bb = (const uint4*)(base + (size_t)blockIdx.x * PK);
    const uint4* gg = (const uint4*)(goff + (size_t)(blockIdx.x >> 6) * PK);
    for (int i = t; i < PK / 4; i += 1024) {
        uint4 b = bb[i], o = gg[i];
        // byte-parallel add: per-row sums < 256 so no cross-byte carries
        ((uint4*)cur)[i] = make_uint4(b.x + o.x, b.y + o.y, b.z + o.z, b.w + o.w);
    }
    __syncthreads();
    int e0 = blockIdx.x * EPB;
    for (int i = t; i < EPB; i += 1024) {
        int e = e0 + i;
        int r = rows[e];
        unsigned sh = (unsigned)(r & 3) * 8u;
        unsigned old = atomicAdd(&cur[r >> 2], 1u << sh);   // LDS atomic
        int pos = row_start[r] + (int)((old >> sh) & 0xffu);
        csr_cv[pos] = ((unsigned)cols[e] << 16) | bf16bits(vals[e]);
    }
}

// ---------------- SpMM (CSR, quarter-wave per edge, 16-edge unrolled gathers) ----------------
// lane = 16p+q: p = edge-of-quad, q = dim group of 8 (one 16B chunk of the row).
// Inner loop handles 16 edges (4 quads) per iteration: FOUR independent dwordx4
// gathers in flight per lane. Zero-padding beyond cnt (u=0 -> col 0, val +0.0)
// makes over-run exact; pad gathers broadcast row 0 (L1 hit).
// Hout store is a NORMAL cached store — it is the NEXT hop's gather source.
// MODE 0: Hout[r] = bf16(acc)                               (hop 2)
// MODE 1: Hout[r] = bf16(0.5*acc)                           (hop 1, folds input scale)
// MODE 2: Hout[r] = bf16(0.5*feats[r] + h1[r] + h2[r] + acc)   (hop 3, y in bf16)
template <int MODE>
__global__ __launch_bounds__(256) void spmm_csr(const int* __restrict__ row_start,
                                                const unsigned* __restrict__ csr_cv,
                                                const uintx4* __restrict__ Hin4,
                                                uintx4* __restrict__ Hout4,
                                                const float* __restrict__ feats,
                                                const uintx4* __restrict__ h1b4,
                                                const uintx4* __restrict__ h2b4) {
    int wave = (blockIdx.x * blockDim.x + threadIdx.x) >> 6;
    int lane = threadIdx.x & 63;
    if (wave >= N_NODES) return;
    int p = lane >> 4;          // 0..3: which edge of the quad
    int q = lane & 15;          // dim group (8 dims = 16 B)
    int start = row_start[wave];
    int end   = row_start[wave + 1];
    float acc[8] = {};
    for (int base = start; base < end; base += 64) {
        int idx = base + lane;
        unsigned u = 0;                         // col=0, val=+0.0 padding
        if (idx < end) u = __builtin_nontemporal_load(csr_cv + idx);
        int cnt = min(64, end - base);
        for (int j = 0; j < cnt; j += 16) {
            unsigned uj0 = __shfl(u, j + p);
            unsigned uj1 = __shfl(u, j + 4 + p);
            unsigned uj2 = __shfl(u, j + 8 + p);
            unsigned uj3 = __shfl(u, j + 12 + p);   // <= 63: ok
            int c0 = uj0 >> 16, c1 = uj1 >> 16, c2 = uj2 >> 16, c3 = uj3 >> 16;
            float v0 = __uint_as_float(uj0 << 16);
            float v1 = __uint_as_float(uj1 << 16);
            float v2 = __uint_as_float(uj2 << 16);
            float v3 = __uint_as_float(uj3 << 16);
            uintx4 h0 = Hin4[(size_t)c0 * 16 + q];   // 4 independent gathers in flight
            uintx4 h1 = Hin4[(size_t)c1 * 16 + q];
            uintx4 h2 = Hin4[(size_t)c2 * 16 + q];
            uintx4 h3 = Hin4[(size_t)c3 * 16 + q];
            FMA8(acc, v0, h0);
            FMA8(acc, v1, h1);
            FMA8(acc, v2, h2);
            FMA8(acc, v3, h3);
        }
    }
    // reduce the 4 edge-subsets (lane bits 4..5)
    #pragma unroll
    for (int i = 0; i < 8; ++i) {
        acc[i] += __shfl_xor(acc[i], 16);
        acc[i] += __shfl_xor(acc[i], 32);
    }
    if (p == 0) {
        size_t o16 = (size_t)wave * 16 + q;
        if (MODE == 1) {
            #pragma unroll
            for (int i = 0; i < 8; ++i) acc[i] *= 0.5f;
        } else if (MODE == 2) {
            size_t of = (size_t)wave * IN_DIM + q * 8;
            floatx4 f0 = __builtin_nontemporal_load((const floatx4*)(feats + of));
            floatx4 f1 = __builtin_nontemporal_load((const floatx4*)(feats + of + 4));
            uintx4 a = __builtin_nontemporal_load(h1b4 + o16);
            uintx4 b = __builtin_nontemporal_load(h2b4 + o16);
            acc[0] += 0.5f * f0.x + bf_lo(a.x) + bf_lo(b.x);
            acc[1] += 0.5f * f0.y + bf_hi(a.x) + bf_hi(b.x);
            acc[2] += 0.5f * f0.z + bf_lo(a.y) + bf_lo(b.y);
            acc[3] += 0.5f * f0.w + bf_hi(a.y) + bf_hi(b.y);
            acc[4] += 0.5f * f1.x + bf_lo(a.z) + bf_lo(b.z);
            acc[5] += 0.5f * f1.y + bf_hi(a.z) + bf_hi(b.z);
            acc[6] += 0.5f * f1.z + bf_lo(a.w) + bf_lo(b.w);
            acc[7] += 0.5f * f1.w + bf_hi(a.w) + bf_hi(b.w);
        }
        uintx4 rv;
        rv.x = bf16pair(acc[0], acc[1]);
        rv.y = bf16pair(acc[2], acc[3]);
        rv.z = bf16pair(acc[4], acc[5]);
        rv.w = bf16pair(acc[6], acc[7]);
        Hout4[o16] = rv;          // cached store: next hop gathers from this buffer
    }
}

// ---------------- fused MLP v3: 32 rows/block (2x blocks), col-split gemm1 ----------
// 1563 blocks x 4 waves. gemm1: wave w handles row-group w>>1 (16 rows) and col-half
// w&1 (128 cols) -> 32 MFMAs/wave (vs 64), 2x block-level parallelism. LDS tile is
// 16.5 KB -> 8 blocks/CU LDS-wise. One barrier (col-half exchange). gemm2 + double
// log_softmax on waves 0-1 (16 rows each); waves 2-3 exit.
#define H1_STRIDE 264   // ushorts per row (132 u32)
__global__ __launch_bounds__(256) void mlp_fused(const uint4* __restrict__ yb4,
                                                 const uint4* __restrict__ W1frag,
                                                 const uint4* __restrict__ W2frag,
                                                 const float* __restrict__ bias1,
                                                 const float* __restrict__ b2,
                                                 float* __restrict__ Out) {
    __shared__ unsigned short h1u[32 * H1_STRIDE];    // 16.5 KB: H1 tile, bf16
    int tid = threadIdx.x;
    int w = tid >> 6, lane = tid & 63;
    int q = lane >> 4, c16 = lane & 15;
    int rg = w >> 1;            // row group (0/1)
    int ch = w & 1;             // col half (0/1)
    int row0 = blockIdx.x * 32;
    int arow = row0 + rg * 16 + c16;

    union { uint4 u; short8 v; } au[4], bu, af;
    if (arow < N_NODES) {
        #pragma unroll
        for (int s = 0; s < 4; ++s)
            au[s].u = yb4[(size_t)arow * 16 + 4 * s + q];
    } else {
        #pragma unroll
        for (int s = 0; s < 4; ++s)
            au[s].u = make_uint4(0u, 0u, 0u, 0u);
    }

    // ---- gemm1: 8 col-tiles of this wave's half, B-frags straight from L2 ----
    #pragma unroll 4
    for (int tt = 0; tt < 8; ++tt) {
        floatx4 acc = {0.f, 0.f, 0.f, 0.f};
        #pragma unroll
        for (int s = 0; s < 4; ++s) {
            bu.u = W1frag[((ch * 8 + tt) * 4 + s) * 64 + lane];
            acc = __builtin_amdgcn_mfma_f32_16x16x32_bf16(au[s].v, bu.v, acc, 0, 0, 0);
        }
        int col = ch * 128 + tt * 16 + c16;
        float bs = bias1[col];
        #pragma unroll
        for (int r = 0; r < 4; ++r) {
            float v = 0.25f * acc[r] + bs;
            v = v > 0.f ? v : 0.f;
            h1u[(rg * 16 + q * 4 + r) * H1_STRIDE + col] = (unsigned short)bf16bits(v);
        }
    }
    __syncthreads();   // col-half exchange
    if (w >= 2) return;   // waves 2,3 done

    // ---- gemm2: wave w owns rows w*16..w*16+15; B-frags straight from L2 ----
    floatx4 acc2[3] = {{0.f,0.f,0.f,0.f},{0.f,0.f,0.f,0.f},{0.f,0.f,0.f,0.f}};
    const unsigned* h1w = (const unsigned*)h1u;
    #pragma unroll
    for (int ks = 0; ks < 8; ++ks) {
        af.u = *(const uint4*)&h1w[(w * 16 + c16) * (H1_STRIDE / 2) + ks * 16 + q * 4];
        #pragma unroll
        for (int nt = 0; nt < 3; ++nt) {
            bu.u = W2frag[nt * 512 + ks * 64 + lane];
            acc2[nt] = __builtin_amdgcn_mfma_f32_16x16x32_bf16(af.v, bu.v, acc2[nt], 0, 0, 0);
        }
    }

    // ---- +b2, double log_softmax (rows span 16-lane groups), write ----
    float bb[3];
    #pragma unroll
    for (int nt = 0; nt < 3; ++nt) {
        int col = nt * 16 + c16;
        bb[nt] = (col < NCLASS) ? b2[col] : 0.f;
    }
    #pragma unroll
    for (int r = 0; r < 4; ++r) {
        int gr = row0 + w * 16 + q * 4 + r;
        float z[3];
        #pragma unroll
        for (int nt = 0; nt < 3; ++nt) z[nt] = acc2[nt][r] + bb[nt];
        if (c16 >= 8) z[2] = -INFINITY;   // cols 40..47 are padding
        float m = fmaxf(fmaxf(z[0], z[1]), z[2]);
        #pragma unroll
        for (int off = 1; off < 16; off <<= 1) m = fmaxf(m, __shfl_xor(m, off));
        float s = expf(z[0] - m) + expf(z[1] - m) + ((c16 < 8) ? expf(z[2] - m) : 0.f);
        #pragma unroll
        for (int off = 1; off < 16; off <<= 1) s += __shfl_xor(s, off);
        float l1 = m + logf(s);
        #pragma unroll
        for (int nt = 0; nt < 3; ++nt) z[nt] -= l1;
        float m2 = fmaxf(fmaxf(z[0], z[1]), z[2]);
        #pragma unroll
        for (int off = 1; off < 16; off <<= 1) m2 = fmaxf(m2, __shfl_xor(m2, off));
        float s2 = expf(z[0] - m2) + expf(z[1] - m2) + ((c16 < 8) ? expf(z[2] - m2) : 0.f);
        #pragma unroll
        for (int off = 1; off < 16; off <<= 1) s2 += __shfl_xor(s2, off);
        float l2 = m2 + logf(s2);
        if (gr < N_NODES) {
            #pragma unroll
            for (int nt = 0; nt < 3; ++nt) {
                int col = nt * 16 + c16;
                if (col < NCLASS)
                    Out[(size_t)gr * NCLASS + col] = z[nt] - l2;
            }
        }
    }
}

extern "C" void kernel_launch(void* const* d_in, const int* in_sizes, int n_in,
                              void* d_out, int out_size, void* d_ws, size_t ws_size,
                              hipStream_t stream) {
    const float* feats   = (const float*)d_in[0];
    const int*   e_row   = (const int*)d_in[1];
    const int*   e_col   = (const int*)d_in[2];
    const float* e_vals  = (const float*)d_in[3];
    const float* W1      = (const float*)d_in[4];
    const float* b1      = (const float*)d_in[5];
    const float* W2      = (const float*)d_in[6];
    const float* b2      = (const float*)d_in[7];
    float* out = (float*)d_out;

    // Workspace (19.2M floats proven):
    //   hist  : [0, 3.2M)           256 x 12500 packed u32 (12.8 MB; dead after colscan)
    //   ybf   : [0, 3.2M)           y in bf16 (MLP input, written by hop3)
    //   W1frag: [3.2M, 3.217M)      W1 bf16 MFMA fragments (64 KB)
    //   W2frag: [3.25M, 3.257M)     W2 bf16 MFMA fragments (24 KB)
    //   counts: [3.3M, 3.35M)       per-row degrees (dead after local_scan)
    //   goff  : [3.4M, 3.45M)       colscan group offsets (dead after scatter)
    //   fb16  : [6.4M, 9.6M)        feats in bf16
    //   h1b   : [9.6M, 12.8M)       hop1 out, bf16
    //   h2b   : [12.8M, 16M)        hop2 out, bf16
    //   base  : [16M, 19.2M)        per-(block,row) packed bases (dead after scatter)
    float* ws    = (float*)d_ws;
    uint4* ybf4  = (uint4*)ws;
    unsigned* hist = (unsigned*)ws;
    uint4* W1frag = (uint4*)(ws + (size_t)N_NODES * IN_DIM / 2);
    uint4* W2frag = (uint4*)(ws + 3250000);
    int*   counts = (int*)(ws + 3300000);
    unsigned* goff = (unsigned*)(ws + 3400000);
    uint4* fb16_4 = (uint4*)(ws + (size_t)N_NODES * IN_DIM);
    uint4* h1b4  = (uint4*)(ws + (size_t)N_NODES * IN_DIM * 3 / 2);
    uint4* h2b4  = (uint4*)(ws + (size_t)N_NODES * IN_DIM * 2);
    unsigned* basep = (unsigned*)(ws + (size_t)N_NODES * IN_DIM * 5 / 2);   // 16M..19.2M

    // CSR scratch in d_out (8 MB; fully overwritten by mlp_fused at the end).
    unsigned* csr_cv = (unsigned*)d_out;                 // packed (col<<16)|bf16(val), 800000
    int*   row_start = (int*)d_out + 2 * N_EDGES;        // [1600000, 1650001)
    int*   blockSums = row_start + N_NODES + 4;          // < 2000000

    // fused prep + hist: feats->bf16, W1/W2 frag pack, privatized LDS histograms
    prep_hist_kernel<<<HBLK, 1024, 0, stream>>>((const float4*)feats, (uint2*)fb16_4,
                                                W1, W1frag, W2, W2frag, e_row, hist);

    // CSR build, zero global atomics
    colscan_kernel<<<SCAN_NBLK, 1024, 0, stream>>>(hist, basep, goff, counts, blockSums);
    local_scan_kernel<<<SCAN_NBLK, 256, 0, stream>>>(counts, blockSums, row_start);
    scatter2_kernel<<<HBLK, 1024, 0, stream>>>(e_row, e_col, e_vals, basep, goff,
                                               row_start, csr_cv);

    // 3 propagation hops (quarter-wave per edge, 16-edge unrolled: 4 gathers in flight)
    const int SPMM_BLOCKS = N_NODES / 4;      // 12500 (4 waves/block)
    spmm_csr<1><<<SPMM_BLOCKS, 256, 0, stream>>>(row_start, csr_cv, (const uintx4*)fb16_4,
                                                 (uintx4*)h1b4, nullptr, nullptr, nullptr);
    spmm_csr<0><<<SPMM_BLOCKS, 256, 0, stream>>>(row_start, csr_cv, (const uintx4*)h1b4,
                                                 (uintx4*)h2b4, nullptr, nullptr, nullptr);
    spmm_csr<2><<<SPMM_BLOCKS, 256, 0, stream>>>(row_start, csr_cv, (const uintx4*)h2b4,
                                                 (uintx4*)ybf4, feats,
                                                 (const uintx4*)h1b4, (const uintx4*)h2b4);

    // fused MLP v3: relu(0.25*(ybf@W1)+b1) @ W2 + b2 -> double log_softmax -> out
    mlp_fused<<<(N_NODES + 31) / 32, 256, 0, stream>>>(ybf4, W1frag, W2frag, b1, b2, out);
}